// Round 1
// baseline (114.007 us; speedup 1.0000x reference)
//
#include <hip/hip_runtime.h>
#include <math.h>

constexpr int   NUM_RES = 2048;
constexpr float CUTOFF  = 10.0f;

__device__ __forceinline__ int lower_bound_i32(const int* __restrict__ arr, int n, int key) {
    int lo = 0, hi = n;
    while (lo < hi) {
        int mid = (lo + hi) >> 1;
        if (arr[mid] < key) lo = mid + 1; else hi = mid;
    }
    return lo;
}

// Determine whether is_mutation is stored as uint8 (1 B/elem) or int32 (4 B/elem).
// We scan only the first n bytes (safe under both layouts). If int32 with 0/1
// values, every byte at i%4 != 0 is zero. If uint8, ~1% of all bytes are 1, so
// some byte at i%4 != 0 is almost surely nonzero -> flag = 1 means uint8.
__global__ void detect_mut_dtype(const unsigned char* __restrict__ mut, int n,
                                 int* __restrict__ flag) {
    int acc = 0;
    for (int i = blockIdx.x * blockDim.x + threadIdx.x; i < n;
         i += blockDim.x * gridDim.x) {
        if ((i & 3) != 0 && mut[i] != 0) acc = 1;
    }
    if (acc) atomicOr(flag, 1);
}

// One thread per atom (both directions). Finds nearest opposite-side atom in
// the same graph (contiguous range since node2graph is sorted), writes the
// distance, and atomically sets the residue interface flag if dist < CUTOFF.
__global__ void nearest_kernel(const float* __restrict__ pos_a,
                               const float* __restrict__ pos_b,
                               const int* __restrict__ n2g_a,
                               const int* __restrict__ n2g_b,
                               const int* __restrict__ a2r_a,
                               const int* __restrict__ a2r_b,
                               int Na, int Nb,
                               float* __restrict__ out_dists,
                               int* __restrict__ res_flags) {
    int tid = blockIdx.x * blockDim.x + threadIdx.x;
    int Ntot = Na + Nb;
    if (tid >= Ntot) return;

    const float* ps; const float* po;
    const int* n2g_s; const int* n2g_o; const int* a2r;
    int i, n_opp, side;
    if (tid < Na) {
        side = 0; i = tid;
        ps = pos_a; po = pos_b; n2g_s = n2g_a; n2g_o = n2g_b;
        a2r = a2r_a; n_opp = Nb;
    } else {
        side = 1; i = tid - Na;
        ps = pos_b; po = pos_a; n2g_s = n2g_b; n2g_o = n2g_a;
        a2r = a2r_b; n_opp = Na;
    }

    float x = ps[3 * i + 0];
    float y = ps[3 * i + 1];
    float z = ps[3 * i + 2];
    int g  = n2g_s[i];
    int lo = lower_bound_i32(n2g_o, n_opp, g);
    int hi = lower_bound_i32(n2g_o, n_opp, g + 1);

    // jnp.argmin over an all-inf row returns 0 -> init best = 0. Strict `<`
    // in ascending order matches argmin's first-occurrence tie-break.
    int   best   = 0;
    float bestd2 = INFINITY;
    for (int j = lo; j < hi; ++j) {
        float dx = x - po[3 * j + 0];
        float dy = y - po[3 * j + 1];
        float dz = z - po[3 * j + 2];
        float d2 = dx * dx + dy * dy + dz * dz;
        if (d2 < bestd2) { bestd2 = d2; best = j; }
    }

    // Recompute the norm at the argmin exactly like the reference does.
    float dx = x - po[3 * best + 0];
    float dy = y - po[3 * best + 1];
    float dz = z - po[3 * best + 2];
    float dist = sqrtf(dx * dx + dy * dy + dz * dz);

    out_dists[tid] = dist;
    if (dist < CUTOFF) {
        atomicOr(&res_flags[side * NUM_RES + a2r[i]], 1);
    }
}

__global__ void mask_kernel(const void* __restrict__ mut,
                            const int* __restrict__ a2r_a,
                            const int* __restrict__ a2r_b,
                            int Na, int Nb,
                            const int* __restrict__ res_flags,
                            const int* __restrict__ mut_is_u8,
                            float* __restrict__ out_mask) {
    int tid = blockIdx.x * blockDim.x + threadIdx.x;
    int Ntot = Na + Nb;
    if (tid >= Ntot) return;

    int side = (tid < Na) ? 0 : 1;
    int i    = (tid < Na) ? tid : tid - Na;
    int r    = side ? a2r_b[i] : a2r_a[i];
    int iface = res_flags[side * NUM_RES + r];

    int m;
    if (*mut_is_u8) {
        m = ((const unsigned char*)mut)[tid] != 0;
    } else {
        m = ((const int*)mut)[tid] != 0;
    }
    out_mask[tid] = (iface || m) ? 1.0f : 0.0f;
}

extern "C" void kernel_launch(void* const* d_in, const int* in_sizes, int n_in,
                              void* d_out, int out_size, void* d_ws, size_t ws_size,
                              hipStream_t stream) {
    const float* pos_a = (const float*)d_in[0];
    const float* pos_b = (const float*)d_in[1];
    const int*   n2g_a = (const int*)d_in[2];
    const int*   n2g_b = (const int*)d_in[3];
    const int*   a2r_a = (const int*)d_in[4];
    const int*   a2r_b = (const int*)d_in[5];
    const void*  mut   = d_in[6];

    int Na = in_sizes[0] / 3;
    int Nb = in_sizes[1] / 3;
    int Ntot = Na + Nb;

    float* out = (float*)d_out;           // [0, Ntot) mask, [Ntot, 2*Ntot) dists
    int* res_flags = (int*)d_ws;          // 2 * NUM_RES ints
    int* mut_flag  = res_flags + 2 * NUM_RES;

    hipMemsetAsync(d_ws, 0, (2 * NUM_RES + 1) * sizeof(int), stream);

    detect_mut_dtype<<<32, 256, 0, stream>>>((const unsigned char*)mut, Ntot, mut_flag);

    int blocks = (Ntot + 255) / 256;
    nearest_kernel<<<blocks, 256, 0, stream>>>(pos_a, pos_b, n2g_a, n2g_b,
                                               a2r_a, a2r_b, Na, Nb,
                                               out + Ntot, res_flags);

    mask_kernel<<<blocks, 256, 0, stream>>>(mut, a2r_a, a2r_b, Na, Nb,
                                            res_flags, mut_flag, out);
}

// Round 2
// 87.861 us; speedup vs baseline: 1.2976x; 1.2976x over previous
//
#include <hip/hip_runtime.h>
#include <math.h>

constexpr int   NUM_RES = 2048;
constexpr float CUTOFF  = 10.0f;
constexpr int   NGRAPH  = 64;

__device__ __forceinline__ int lower_bound_i32(const int* __restrict__ arr, int n, int key) {
    int lo = 0, hi = n;
    while (lo < hi) {
        int mid = (lo + hi) >> 1;
        if (arr[mid] < key) lo = mid + 1; else hi = mid;
    }
    return lo;
}

// ws layout (ints): [0,4096) res_flags, [4096] mut_flag,
//                   [4097,4162) starts_a (65), [4162,4227) starts_b (65)
constexpr int WS_FLAGS   = 0;
constexpr int WS_MUTFLAG = 4096;
constexpr int WS_STARTS_A = 4097;
constexpr int WS_STARTS_B = 4162;

// One kernel: zero residue flags, detect is_mutation storage width
// (uint8 vs int32), and build per-graph start-offset tables for both sides.
__global__ void init_kernel(const unsigned char* __restrict__ mut, int Ntot,
                            const int* __restrict__ n2g_a, int Na,
                            const int* __restrict__ n2g_b, int Nb,
                            int* __restrict__ ws) {
    int tid = blockIdx.x * blockDim.x + threadIdx.x;
    int nthreads = blockDim.x * gridDim.x;

    // zero flags + mut_flag
    for (int i = tid; i < 2 * NUM_RES + 1; i += nthreads) ws[WS_FLAGS + i] = 0;

    // graph range tables: g in [0, NGRAPH] inclusive (65 entries each side)
    if (tid >= 8192 && tid < 8192 + (NGRAPH + 1))
        ws[WS_STARTS_A + (tid - 8192)] = lower_bound_i32(n2g_a, Na, tid - 8192);
    if (tid >= 8320 && tid < 8320 + (NGRAPH + 1))
        ws[WS_STARTS_B + (tid - 8320)] = lower_bound_i32(n2g_b, Nb, tid - 8320);

    // dtype detect: if int32 with 0/1 payloads, every byte at i%4!=0 is 0;
    // if uint8, ~1% of bytes are 1 so some i%4!=0 byte is nonzero.
    int acc = 0;
    for (int i = tid; i < Ntot; i += nthreads)
        if ((i & 3) != 0 && mut[i] != 0) acc = 1;
    if (acc) atomicOr(&ws[WS_MUTFLAG], 1);
}

// One WAVE per atom (both directions). Lanes scan the opposite-side graph
// range in parallel (stride 64), then shuffle-reduce the (d2, idx) argmin.
__global__ void nearest_kernel(const float* __restrict__ pos_a,
                               const float* __restrict__ pos_b,
                               const int* __restrict__ n2g_a,
                               const int* __restrict__ n2g_b,
                               const int* __restrict__ a2r_a,
                               const int* __restrict__ a2r_b,
                               int Na, int Nb,
                               float* __restrict__ out_dists,
                               int* __restrict__ ws) {
    int lane    = threadIdx.x & 63;
    int wave_id = (blockIdx.x * blockDim.x + threadIdx.x) >> 6;
    int Ntot = Na + Nb;
    if (wave_id >= Ntot) return;

    const float* ps; const float* po;
    const int* n2g_s; const int* a2r; const int* starts_o;
    int i, side;
    if (wave_id < Na) {
        side = 0; i = wave_id;
        ps = pos_a; po = pos_b; n2g_s = n2g_a; a2r = a2r_a;
        starts_o = ws + WS_STARTS_B;
    } else {
        side = 1; i = wave_id - Na;
        ps = pos_b; po = pos_a; n2g_s = n2g_b; a2r = a2r_b;
        starts_o = ws + WS_STARTS_A;
    }

    float x = ps[3 * i + 0];
    float y = ps[3 * i + 1];
    float z = ps[3 * i + 2];
    int g  = n2g_s[i];
    int lo = starts_o[g];
    int hi = starts_o[g + 1];

    // lane-local scan (ascending j per lane; strict < = first occurrence)
    int   best   = 0;
    float bestd2 = INFINITY;
    for (int j = lo + lane; j < hi; j += 64) {
        float dx = x - po[3 * j + 0];
        float dy = y - po[3 * j + 1];
        float dz = z - po[3 * j + 2];
        float d2 = dx * dx + dy * dy + dz * dz;
        if (d2 < bestd2) { bestd2 = d2; best = j; }
    }

    // cross-lane argmin: smaller d2 wins; tie -> smaller index (first occ.)
    for (int off = 32; off >= 1; off >>= 1) {
        float od2 = __shfl_down(bestd2, off, 64);
        int   oj  = __shfl_down(best,   off, 64);
        if (od2 < bestd2 || (od2 == bestd2 && oj < best)) {
            bestd2 = od2; best = oj;
        }
    }

    if (lane == 0) {
        // recompute the norm at the argmin exactly like the reference
        float dx = x - po[3 * best + 0];
        float dy = y - po[3 * best + 1];
        float dz = z - po[3 * best + 2];
        float dist = sqrtf(dx * dx + dy * dy + dz * dz);
        out_dists[wave_id] = dist;
        if (dist < CUTOFF) {
            // benign idempotent race: everyone writes 1
            ws[WS_FLAGS + side * NUM_RES + a2r[i]] = 1;
        }
    }
}

__global__ void mask_kernel(const void* __restrict__ mut,
                            const int* __restrict__ a2r_a,
                            const int* __restrict__ a2r_b,
                            int Na, int Nb,
                            const int* __restrict__ ws,
                            float* __restrict__ out_mask) {
    int tid = blockIdx.x * blockDim.x + threadIdx.x;
    int Ntot = Na + Nb;
    if (tid >= Ntot) return;

    int side = (tid < Na) ? 0 : 1;
    int i    = (tid < Na) ? tid : tid - Na;
    int r    = side ? a2r_b[i] : a2r_a[i];
    int iface = ws[WS_FLAGS + side * NUM_RES + r];

    int m;
    if (ws[WS_MUTFLAG]) {
        m = ((const unsigned char*)mut)[tid] != 0;
    } else {
        m = ((const int*)mut)[tid] != 0;
    }
    out_mask[tid] = (iface || m) ? 1.0f : 0.0f;
}

extern "C" void kernel_launch(void* const* d_in, const int* in_sizes, int n_in,
                              void* d_out, int out_size, void* d_ws, size_t ws_size,
                              hipStream_t stream) {
    const float* pos_a = (const float*)d_in[0];
    const float* pos_b = (const float*)d_in[1];
    const int*   n2g_a = (const int*)d_in[2];
    const int*   n2g_b = (const int*)d_in[3];
    const int*   a2r_a = (const int*)d_in[4];
    const int*   a2r_b = (const int*)d_in[5];
    const void*  mut   = d_in[6];

    int Na = in_sizes[0] / 3;
    int Nb = in_sizes[1] / 3;
    int Ntot = Na + Nb;

    float* out = (float*)d_out;   // [0, Ntot) mask, [Ntot, 2*Ntot) dists
    int* ws = (int*)d_ws;

    init_kernel<<<64, 256, 0, stream>>>((const unsigned char*)mut, Ntot,
                                        n2g_a, Na, n2g_b, Nb, ws);

    // one wave (64 lanes) per atom; 256-thread blocks = 4 atoms/block
    int nblocks = (Ntot * 64 + 255) / 256;
    nearest_kernel<<<nblocks, 256, 0, stream>>>(pos_a, pos_b, n2g_a, n2g_b,
                                                a2r_a, a2r_b, Na, Nb,
                                                out + Ntot, ws);

    mask_kernel<<<(Ntot + 255) / 256, 256, 0, stream>>>(mut, a2r_a, a2r_b,
                                                        Na, Nb, ws, out);
}